// Round 6
// baseline (191.659 us; speedup 1.0000x reference)
//
#include <hip/hip_runtime.h>

typedef float f4 __attribute__((ext_vector_type(4)));

// tanh(x) = 1 - 2/(exp(2x)+1), using hw v_exp_f32 (computes 2^x) and v_rcp_f32.
// Saturates correctly: x->+inf => e=inf => rcp=0 => 1; x->-inf => e=0 => -1.
__device__ __forceinline__ float fast_tanh(float x) {
    float e = __builtin_amdgcn_exp2f(x * 2.8853900817779268f);
    float r = __builtin_amdgcn_rcpf(e + 1.0f);
    return 1.0f - 2.0f * r;
}

__device__ __forceinline__ f4 shfl_xor1(f4 v) {
    f4 r;
    r.x = __shfl_xor(v.x, 1, 64);
    r.y = __shfl_xor(v.y, 1, 64);
    r.z = __shfl_xor(v.z, 1, 64);
    r.w = __shfl_xor(v.w, 1, 64);
    return r;
}

__device__ __forceinline__ float rnn_one(
    const f4 lo, const f4 hi,
    float w00, float w01, float w10, float w11, float bi0, float bi1,
    float u00, float u01, float u10, float u11, float bh0, float bh1,
    float c0, float c1, float cb)
{
    float x[8] = {lo.x, lo.y, lo.z, lo.w, hi.x, hi.y, hi.z, hi.w};
    float h0 = 0.0f, h1 = 0.0f;
#pragma unroll
    for (int t = 0; t < 4; ++t) {
        float xt0 = x[2 * t], xt1 = x[2 * t + 1];
        float p0 = fmaf(w00, xt0, fmaf(w01, xt1, bi0));
        float p1 = fmaf(w10, xt0, fmaf(w11, xt1, bi1));
        float n0 = fast_tanh(p0 + fmaf(u00, h0, fmaf(u01, h1, bh0)));
        float n1 = fast_tanh(p1 + fmaf(u10, h0, fmaf(u11, h1, bh1)));
        h0 = n0;
        h1 = n1;
    }
    return fmaf(c0, h0, fmaf(c1, h1, cb));
}

// R5 resubmit (R5 bench was an infra failure — container died, kernel never ran).
// Single variable vs R4: loads are DEFAULT allocating device-scope instead of
// `sc0 sc1 nt`. Rationale from harness counters: the poison fill (WRITE 488
// MiB) and the X-restore copy (WRITE 125 MB) both drain their writebacks
// in-window, so at kernel start X's 128 MB is clean and most-recently-touched
// in the 256 MiB Infinity Cache. Allocating reads of the SAME lines the copy
// just wrote should hit MALL (no new eviction traffic); sc0sc1nt forced those
// reads to HBM. Store stays nt (out written once; don't displace anything).
// Layout kept from R4: per wave, two fully-contiguous 1 KB load instructions
// + one shfl_xor(1) to re-pair halves; even lane 2k owns sample sb+k, odd
// lane 2k+1 owns sample sb+32+k.
__global__ __launch_bounds__(256) void rnn2_cls_kernel(
    const float* __restrict__ X,       // [B,4,2]
    const float* __restrict__ w_ih,    // [2,2] row-major: w_ih[h*2+d]
    const float* __restrict__ b_ih,    // [2]
    const float* __restrict__ w_hh,    // [2,2]
    const float* __restrict__ b_hh,    // [2]
    const float* __restrict__ cls_w,   // [1,2]
    const float* __restrict__ cls_b,   // [1]
    float* __restrict__ out,           // [B]
    int B)
{
    const int lane = (int)(threadIdx.x & 63);
    const long long wave = (((long long)blockIdx.x * blockDim.x) + threadIdx.x) >> 6;
    const long long sb = wave * 64;    // first sample owned by this wave
    if (sb >= B) return;

    // Uniform-address parameter loads: scalar-cached, negligible traffic.
    const float w00 = w_ih[0], w01 = w_ih[1], w10 = w_ih[2], w11 = w_ih[3];
    const float bi0 = b_ih[0], bi1 = b_ih[1];
    const float u00 = w_hh[0], u01 = w_hh[1], u10 = w_hh[2], u11 = w_hh[3];
    const float bh0 = b_hh[0], bh1 = b_hh[1];
    const float c0 = cls_w[0], c1 = cls_w[1], cb = cls_b[0];

    const f4* X4 = reinterpret_cast<const f4*>(X);

    if (sb + 64 <= B) {
        // Two contiguous 1 KB wave loads: float4s [2*sb+lane] and [2*sb+64+lane].
        const f4* p = X4 + 2 * sb + lane;
        f4 v0 = p[0];     // default allocating load — can hit MALL-resident X
        f4 v1 = p[64];    // +1024 B

        f4 w0 = shfl_xor1(v0);   // partner lane's half of my sample
        f4 w1 = shfl_xor1(v1);

        f4 lo, hi;
        long long s;
        if ((lane & 1) == 0) {   // even lane 2k -> sample sb+k (from v0 pair)
            lo = v0; hi = w0; s = sb + (lane >> 1);
        } else {                 // odd lane 2k+1 -> sample sb+32+k (from v1 pair)
            lo = w1; hi = v1; s = sb + 32 + (lane >> 1);
        }

        float o = rnn_one(lo, hi, w00, w01, w10, w11, bi0, bi1,
                          u00, u01, u10, u11, bh0, bh1, c0, c1, cb);
        __builtin_nontemporal_store(o, out + s);
    } else {
        // Tail wave (B % 64 != 0): per-thread addressing, default loads.
        long long s = sb + lane;
        if (s < B) {
            f4 lo = X4[2 * s];
            f4 hi = X4[2 * s + 1];
            float o = rnn_one(lo, hi, w00, w01, w10, w11, bi0, bi1,
                              u00, u01, u10, u11, bh0, bh1, c0, c1, cb);
            __builtin_nontemporal_store(o, out + s);
        }
    }
}

extern "C" void kernel_launch(void* const* d_in, const int* in_sizes, int n_in,
                              void* d_out, int out_size, void* d_ws, size_t ws_size,
                              hipStream_t stream) {
    const float* X     = (const float*)d_in[0];
    const float* w_ih  = (const float*)d_in[1];
    const float* b_ih  = (const float*)d_in[2];
    const float* w_hh  = (const float*)d_in[3];
    const float* b_hh  = (const float*)d_in[4];
    const float* cls_w = (const float*)d_in[5];
    const float* cls_b = (const float*)d_in[6];
    float* out = (float*)d_out;

    int B = in_sizes[0] / 8;  // X is [B,4,2]
    long long waves = ((long long)B + 63) / 64;
    long long threads = waves * 64;
    int block = 256;
    int grid = (int)((threads + block - 1) / block);
    rnn2_cls_kernel<<<grid, block, 0, stream>>>(X, w_ih, b_ih, w_hh, b_hh,
                                                cls_w, cls_b, out, B);
}

// Round 7
// 186.747 us; speedup vs baseline: 1.0263x; 1.0263x over previous
//
#include <hip/hip_runtime.h>

typedef float f4 __attribute__((ext_vector_type(4)));

// tanh(x) = 1 - 2/(exp(2x)+1), using hw v_exp_f32 (computes 2^x) and v_rcp_f32.
// Saturates correctly: x->+inf => e=inf => rcp=0 => 1; x->-inf => e=0 => -1.
__device__ __forceinline__ float fast_tanh(float x) {
    float e = __builtin_amdgcn_exp2f(x * 2.8853900817779268f);
    float r = __builtin_amdgcn_rcpf(e + 1.0f);
    return 1.0f - 2.0f * r;
}

__device__ __forceinline__ f4 shfl_xor1(f4 v) {
    f4 r;
    r.x = __shfl_xor(v.x, 1, 64);
    r.y = __shfl_xor(v.y, 1, 64);
    r.z = __shfl_xor(v.z, 1, 64);
    r.w = __shfl_xor(v.w, 1, 64);
    return r;
}

__device__ __forceinline__ float rnn_one(
    const f4 lo, const f4 hi,
    float w00, float w01, float w10, float w11, float bi0, float bi1,
    float u00, float u01, float u10, float u11, float bh0, float bh1,
    float c0, float c1, float cb)
{
    float x[8] = {lo.x, lo.y, lo.z, lo.w, hi.x, hi.y, hi.z, hi.w};
    float h0 = 0.0f, h1 = 0.0f;
#pragma unroll
    for (int t = 0; t < 4; ++t) {
        float xt0 = x[2 * t], xt1 = x[2 * t + 1];
        float p0 = fmaf(w00, xt0, fmaf(w01, xt1, bi0));
        float p1 = fmaf(w10, xt0, fmaf(w11, xt1, bi1));
        float n0 = fast_tanh(p0 + fmaf(u00, h0, fmaf(u01, h1, bh0)));
        float n1 = fast_tanh(p1 + fmaf(u10, h0, fmaf(u11, h1, bh1)));
        h0 = n0;
        h1 = n1;
    }
    return fmaf(c0, h0, fmaf(c1, h1, cb));
}

// FINAL (revert to R4, the best-measured variant: 187.1 µs).
// Experiment matrix across R0-R6 (single-variable each):
//   - load cache policy: sc0 sc1 nt (system-scope non-temporal) beats default
//     allocating by ~4.6 µs — allocating the once-read 128 MB stream into
//     L2/LLC charges eviction writebacks of harness fill/copy lines to our
//     dispatch window. nt store likewise (out written once, never re-read).
//   - per-instruction footprint: two fully-contiguous 1 KB wave loads +
//     shfl_xor(1) re-pairing beats 32 B lane-stride by ~1.4 µs.
//   - samples/thread: SPT=1 beats SPT=4 (~5 µs) — MLP was never the limit;
//     SPT=4's 128 B lane stride broke per-instruction coalescing.
// Remaining total (~187 µs) = harness fill (~74) + X-restore copy (~76) +
// kernel at BW floor (~36 incl. per-iteration small-dispatch overhead).
__global__ __launch_bounds__(256) void rnn2_cls_kernel(
    const float* __restrict__ X,       // [B,4,2]
    const float* __restrict__ w_ih,    // [2,2] row-major: w_ih[h*2+d]
    const float* __restrict__ b_ih,    // [2]
    const float* __restrict__ w_hh,    // [2,2]
    const float* __restrict__ b_hh,    // [2]
    const float* __restrict__ cls_w,   // [1,2]
    const float* __restrict__ cls_b,   // [1]
    float* __restrict__ out,           // [B]
    int B)
{
    const int lane = (int)(threadIdx.x & 63);
    const long long wave = (((long long)blockIdx.x * blockDim.x) + threadIdx.x) >> 6;
    const long long sb = wave * 64;    // first sample owned by this wave
    if (sb >= B) return;

    // Uniform-address parameter loads: scalar-cached, negligible traffic.
    const float w00 = w_ih[0], w01 = w_ih[1], w10 = w_ih[2], w11 = w_ih[3];
    const float bi0 = b_ih[0], bi1 = b_ih[1];
    const float u00 = w_hh[0], u01 = w_hh[1], u10 = w_hh[2], u11 = w_hh[3];
    const float bh0 = b_hh[0], bh1 = b_hh[1];
    const float c0 = cls_w[0], c1 = cls_w[1], cb = cls_b[0];

    const f4* X4 = reinterpret_cast<const f4*>(X);

    if (sb + 64 <= B) {
        // Two contiguous 1 KB wave loads: float4s [2*sb+lane] and [2*sb+64+lane].
        const f4* p = X4 + 2 * sb + lane;
        f4 v0, v1;
        asm volatile(
            "global_load_dwordx4 %0, %2, off sc0 sc1 nt\n\t"
            "global_load_dwordx4 %1, %2, off offset:1024 sc0 sc1 nt\n\t"
            "s_waitcnt vmcnt(0)"
            : "=&v"(v0), "=&v"(v1)
            : "v"(p));

        f4 w0 = shfl_xor1(v0);   // partner lane's half of my sample
        f4 w1 = shfl_xor1(v1);

        f4 lo, hi;
        long long s;
        if ((lane & 1) == 0) {   // even lane 2k -> sample sb+k (from v0 pair)
            lo = v0; hi = w0; s = sb + (lane >> 1);
        } else {                 // odd lane 2k+1 -> sample sb+32+k (from v1 pair)
            lo = w1; hi = v1; s = sb + 32 + (lane >> 1);
        }

        float o = rnn_one(lo, hi, w00, w01, w10, w11, bi0, bi1,
                          u00, u01, u10, u11, bh0, bh1, c0, c1, cb);
        asm volatile("global_store_dword %0, %1, off sc0 sc1 nt"
                     :: "v"(out + s), "v"(o) : "memory");
    } else {
        // Tail wave (B % 64 != 0): per-thread addressing.
        long long s = sb + lane;
        if (s < B) {
            const f4* p = X4 + 2 * s;
            f4 lo, hi;
            asm volatile(
                "global_load_dwordx4 %0, %2, off sc0 sc1 nt\n\t"
                "global_load_dwordx4 %1, %2, off offset:16 sc0 sc1 nt\n\t"
                "s_waitcnt vmcnt(0)"
                : "=&v"(lo), "=&v"(hi)
                : "v"(p));
            float o = rnn_one(lo, hi, w00, w01, w10, w11, bi0, bi1,
                              u00, u01, u10, u11, bh0, bh1, c0, c1, cb);
            asm volatile("global_store_dword %0, %1, off sc0 sc1 nt"
                         :: "v"(out + s), "v"(o) : "memory");
        }
    }
}

extern "C" void kernel_launch(void* const* d_in, const int* in_sizes, int n_in,
                              void* d_out, int out_size, void* d_ws, size_t ws_size,
                              hipStream_t stream) {
    const float* X     = (const float*)d_in[0];
    const float* w_ih  = (const float*)d_in[1];
    const float* b_ih  = (const float*)d_in[2];
    const float* w_hh  = (const float*)d_in[3];
    const float* b_hh  = (const float*)d_in[4];
    const float* cls_w = (const float*)d_in[5];
    const float* cls_b = (const float*)d_in[6];
    float* out = (float*)d_out;

    int B = in_sizes[0] / 8;  // X is [B,4,2]
    long long waves = ((long long)B + 63) / 64;
    long long threads = waves * 64;
    int block = 256;
    int grid = (int)((threads + block - 1) / block);
    rnn2_cls_kernel<<<grid, block, 0, stream>>>(X, w_ih, b_ih, w_hh, b_hh,
                                                cls_w, cls_b, out, B);
}